// Round 4
// baseline (604.079 us; speedup 1.0000x reference)
//
#include <hip/hip_runtime.h>

#define NN 50000
#define EE 800000

typedef __bf16 bf16x8 __attribute__((ext_vector_type(8)));
typedef float  f32x4  __attribute__((ext_vector_type(4)));

__device__ __forceinline__ float bf2f(ushort u) {
    union { unsigned int i; float f; } v; v.i = ((unsigned int)u) << 16; return v.f;
}
__device__ __forceinline__ ushort f2bf(float f) {
    union { float f; unsigned int i; } v; v.f = f;
    unsigned int u = v.i;
    return (ushort)((u + 0x7FFFu + ((u >> 16) & 1u)) >> 16);
}
__device__ __forceinline__ float silu(float x) { return x / (1.0f + __expf(-x)); }

// ---------------------------------------------------------------------------
// Dtype detection: read xz as even-indexed bf16 halves. If the buffer holds
// bf16 coords, every sample decodes to |v|<=4. If it holds f32, the even
// ushorts are f32 mantissa bits -> random exponents -> ~50% insane.
// flag: 0 = bf16 inputs, 1 = f32 inputs.
// ---------------------------------------------------------------------------
__global__ void detect_kernel(const ushort* __restrict__ xzu, int* __restrict__ flag) {
    __shared__ int cnt;
    if (threadIdx.x == 0) cnt = 0;
    __syncthreads();
    float v = bf2f(xzu[2 * threadIdx.x]);
    bool sane = (v == v) && (fabsf(v) <= 4.0f);
    if (sane) atomicAdd(&cnt, 1);
    __syncthreads();
    if (threadIdx.x == 0) *flag = (cnt >= 192) ? 0 : 1;
}

// h -> bf16 copy (for MFMA) + f32 copy (for residual)
__global__ void ingest_h(const void* __restrict__ hsrc, const int* __restrict__ flag,
                         ushort* __restrict__ hb, float* __restrict__ hf) {
    const bool isf = (*flag != 0);
    int i = blockIdx.x * 256 + threadIdx.x;
    if (i >= NN * 128) return;
    if (isf) {
        float v = ((const float*)hsrc)[i];
        hf[i] = v;
        hb[i] = f2bf(v);
    } else {
        ushort u = ((const ushort*)hsrc)[i];
        hf[i] = bf2f(u);
        hb[i] = u;
    }
}

__global__ void ingest_xz(const void* __restrict__ src, const int* __restrict__ flag,
                          float* __restrict__ xzf) {
    const bool isf = (*flag != 0);
    int i = blockIdx.x * 256 + threadIdx.x;
    if (i >= NN * 3) return;
    xzf[i] = isf ? ((const float*)src)[i] : bf2f(((const ushort*)src)[i]);
}

// biases + We1 row 256 -> f32 block: [0:128)=be1 [128:256)=be2 [256:384)=bn1
// [384:512)=bn2 [512:640)=We1[256][:]
__global__ void ingest_misc(const void* be1, const void* be2, const void* bn1, const void* bn2,
                            const void* We1, const int* __restrict__ flag,
                            float* __restrict__ fb) {
    const bool isf = (*flag != 0);
    for (int j = threadIdx.x; j < 640; j += 256) {
        int which = j >> 7, k = j & 127;
        const void* src = (which == 0) ? be1 : (which == 1) ? be2 :
                          (which == 2) ? bn1 : (which == 3) ? bn2 : We1;
        size_t idx = (which == 4) ? ((size_t)256 * 128 + k) : (size_t)k;
        fb[j] = isf ? ((const float*)src)[idx] : bf2f(((const ushort*)src)[idx]);
    }
}

// ---------------------------------------------------------------------------
// Swizzle weights into MFMA B-fragment order (one 16B chunk per lane-frag),
// dual-dtype read.
// ---------------------------------------------------------------------------
__global__ void swizzle_kernel(const void* We1, const void* We2,
                               const void* Wn1, const void* Wn2,
                               const int* __restrict__ flag,
                               ushort* __restrict__ We1s, ushort* __restrict__ We2s,
                               ushort* __restrict__ Wn1s, ushort* __restrict__ Wn2s) {
    const bool isf = (*flag != 0);
    int c = blockIdx.x * blockDim.x + threadIdx.x;   // 12288 chunks
    const void* src; ushort* dst; int cl;
    if      (c <  4096) { src = We1; dst = We1s; cl = c;         }
    else if (c <  6144) { src = We2; dst = We2s; cl = c - 4096;  }
    else if (c < 10240) { src = Wn1; dst = Wn1s; cl = c - 6144;  }
    else if (c < 12288) { src = Wn2; dst = Wn2s; cl = c - 10240; }
    else return;
    int l = cl & 63, nt = (cl >> 6) & 7, kc = cl >> 9;
    int kbase = kc * 32 + (l >> 4) * 8;
    int n = nt * 16 + (l & 15);
    ushort tmp[8];
#pragma unroll
    for (int j = 0; j < 8; ++j) {
        size_t idx = (size_t)(kbase + j) * 128 + n;
        tmp[j] = isf ? f2bf(((const float*)src)[idx]) : ((const ushort*)src)[idx];
    }
#pragma unroll
    for (int j = 0; j < 8; ++j) dst[(size_t)cl * 8 + j] = tmp[j];
}

__global__ void count_kernel(const int* __restrict__ erow, float* __restrict__ cnt) {
    int e = blockIdx.x * 256 + threadIdx.x;
    if (e < EE) unsafeAtomicAdd(&cnt[erow[e]], 1.0f);
}

// ---------------------------------------------------------------------------
// Edge kernel: per 64-edge tile, A = [h[row] | h[col]] (K=256), dist as
// rank-1 epilogue update. m2 -> atomicAdd f32 agg[row].
// ---------------------------------------------------------------------------
__global__ __launch_bounds__(256, 3) void edge_kernel(
    const ushort* __restrict__ hb, const float* __restrict__ xzf,
    const int* __restrict__ erow, const int* __restrict__ ecol,
    const ushort* __restrict__ We1s, const ushort* __restrict__ We2s,
    const float* __restrict__ fb, float* __restrict__ agg) {
    __shared__ __align__(16) ushort sA[16384];   // [g4][kc8][lane64][8]
    __shared__ __align__(16) ushort sM[8192];    // [g4][kc4][lane64][8]
    __shared__ float sDist[64];
    __shared__ int   sRowIdx[64];

    const int tid = threadIdx.x;
    const int lane = tid & 63, w = tid >> 6;
    const int col = lane & 15, quad = lane >> 4;
    const int nt0 = w * 2;

    for (int tile = blockIdx.x; tile < EE / 64; tile += gridDim.x) {
        __syncthreads();
        const int e0 = tile * 64;
        if (tid < 64) {
            int e = e0 + tid;
            int r = erow[e], c = ecol[e];
            sRowIdx[tid] = r;
            float x1 = xzf[3 * r], y1 = xzf[3 * r + 1], z1 = xzf[3 * r + 2];
            float x2 = xzf[3 * c], y2 = xzf[3 * c + 1], z2 = xzf[3 * c + 2];
            float dx = x1 - x2, dy = y1 - y2, dzv = z1 - z2;
            float u = (dx * dx + dy * dy + dzv * dzv) / (2.0f * z1 * z2);
            u = fminf(fmaxf(u, 0.0f), 1.0e6f);
            sDist[tid] = __logf(1.0f + u + sqrtf(u * (u + 2.0f)));   // arccosh(1+u)
        }
#pragma unroll
        for (int i = 0; i < 8; ++i) {
            int cidx = tid + i * 256;
            int m = cidx & 63, kb = cidx >> 6;
            int e = e0 + m;
            int src_node = (kb < 16) ? erow[e] : ecol[e];
            int k0 = (kb & 15) * 8;
            uint4 v = *(const uint4*)(hb + (size_t)src_node * 128 + k0);
            int g = m >> 4, ml = m & 15, kc = kb >> 2, q = kb & 3;
            *(uint4*)(sA + ((g * 8 + kc) * 64 + q * 16 + ml) * 8) = v;
        }
        __syncthreads();

        f32x4 acc[4][2] = {};
#pragma unroll 2
        for (int kc = 0; kc < 8; ++kc) {
            bf16x8 b0 = *(const bf16x8*)(We1s + ((kc * 8 + nt0)     * 64 + lane) * 8);
            bf16x8 b1 = *(const bf16x8*)(We1s + ((kc * 8 + nt0 + 1) * 64 + lane) * 8);
#pragma unroll
            for (int g = 0; g < 4; ++g) {
                bf16x8 a = *(const bf16x8*)(sA + ((g * 8 + kc) * 64 + lane) * 8);
                acc[g][0] = __builtin_amdgcn_mfma_f32_16x16x32_bf16(a, b0, acc[g][0], 0, 0, 0);
                acc[g][1] = __builtin_amdgcn_mfma_f32_16x16x32_bf16(a, b1, acc[g][1], 0, 0, 0);
            }
        }
#pragma unroll
        for (int g = 0; g < 4; ++g) {
#pragma unroll
            for (int t = 0; t < 2; ++t) {
                int n = w * 32 + t * 16 + col;
                float wl = fb[512 + n];
                float bb = fb[n];
                int base = ((g * 4 + w) * 64 + (t * 2 + (col >> 3)) * 16) * 8 + (col & 7);
#pragma unroll
                for (int r = 0; r < 4; ++r) {
                    int mrow = quad * 4 + r;
                    float x = acc[g][t][r] + sDist[g * 16 + mrow] * wl + bb;
                    sM[base + mrow * 8] = f2bf(silu(x));
                }
            }
        }
        __syncthreads();

        f32x4 acc2[4][2] = {};
#pragma unroll
        for (int kc = 0; kc < 4; ++kc) {
            bf16x8 b0 = *(const bf16x8*)(We2s + ((kc * 8 + nt0)     * 64 + lane) * 8);
            bf16x8 b1 = *(const bf16x8*)(We2s + ((kc * 8 + nt0 + 1) * 64 + lane) * 8);
#pragma unroll
            for (int g = 0; g < 4; ++g) {
                bf16x8 a = *(const bf16x8*)(sM + ((g * 4 + kc) * 64 + lane) * 8);
                acc2[g][0] = __builtin_amdgcn_mfma_f32_16x16x32_bf16(a, b0, acc2[g][0], 0, 0, 0);
                acc2[g][1] = __builtin_amdgcn_mfma_f32_16x16x32_bf16(a, b1, acc2[g][1], 0, 0, 0);
            }
        }
#pragma unroll
        for (int g = 0; g < 4; ++g) {
#pragma unroll
            for (int t = 0; t < 2; ++t) {
                int n = w * 32 + t * 16 + col;
                float bb = fb[128 + n];
#pragma unroll
                for (int r = 0; r < 4; ++r) {
                    int m = g * 16 + quad * 4 + r;
                    float x = silu(acc2[g][t][r] + bb);
                    unsafeAtomicAdd(&agg[(size_t)sRowIdx[m] * 128 + n], x);
                }
            }
        }
    }
}

// ---------------------------------------------------------------------------
// Node kernel: z = [h | agg/max(cnt,1)] (K=256); out = h + silu(z@Wn1+bn1)@Wn2+bn2
// Output store branches on detected dtype (wave-uniform).
// ---------------------------------------------------------------------------
__global__ __launch_bounds__(256, 3) void node_kernel(
    const ushort* __restrict__ hb, const float* __restrict__ hf,
    const float* __restrict__ agg, const float* __restrict__ cnt,
    const ushort* __restrict__ Wn1s, const ushort* __restrict__ Wn2s,
    const float* __restrict__ fb, const int* __restrict__ flag,
    void* __restrict__ outv) {
    __shared__ __align__(16) ushort sA[16384];
    __shared__ __align__(16) ushort sM[8192];
    const int tid = threadIdx.x;
    const int lane = tid & 63, w = tid >> 6;
    const int col = lane & 15, quad = lane >> 4;
    const int nt0 = w * 2;
    const int ntiles = (NN + 63) / 64;
    const bool isf = (*flag != 0);
    float* outf = (float*)outv;
    ushort* outu = (ushort*)outv;

    for (int tile = blockIdx.x; tile < ntiles; tile += gridDim.x) {
        __syncthreads();
        const int n0 = tile * 64;
#pragma unroll
        for (int i = 0; i < 8; ++i) {
            int cidx = tid + i * 256;
            int m = cidx & 63, kb = cidx >> 6;
            int node = n0 + m;
            int g = m >> 4, ml = m & 15, kc = kb >> 2, q = kb & 3;
            uint4 v;
            if (node < NN) {
                if (kb < 16) {
                    v = *(const uint4*)(hb + (size_t)node * 128 + kb * 8);
                } else {
                    int kk = (kb - 16) * 8;
                    const float* ap = agg + (size_t)node * 128 + kk;
                    float invc = 1.0f / fmaxf(cnt[node], 1.0f);
                    float4 f0 = *(const float4*)ap;
                    float4 f1 = *(const float4*)(ap + 4);
                    v.x = (unsigned int)f2bf(f0.x * invc) | ((unsigned int)f2bf(f0.y * invc) << 16);
                    v.y = (unsigned int)f2bf(f0.z * invc) | ((unsigned int)f2bf(f0.w * invc) << 16);
                    v.z = (unsigned int)f2bf(f1.x * invc) | ((unsigned int)f2bf(f1.y * invc) << 16);
                    v.w = (unsigned int)f2bf(f1.z * invc) | ((unsigned int)f2bf(f1.w * invc) << 16);
                }
            } else {
                v = make_uint4(0, 0, 0, 0);
            }
            *(uint4*)(sA + ((g * 8 + kc) * 64 + q * 16 + ml) * 8) = v;
        }
        __syncthreads();

        f32x4 acc[4][2] = {};
#pragma unroll 2
        for (int kc = 0; kc < 8; ++kc) {
            bf16x8 b0 = *(const bf16x8*)(Wn1s + ((kc * 8 + nt0)     * 64 + lane) * 8);
            bf16x8 b1 = *(const bf16x8*)(Wn1s + ((kc * 8 + nt0 + 1) * 64 + lane) * 8);
#pragma unroll
            for (int g = 0; g < 4; ++g) {
                bf16x8 a = *(const bf16x8*)(sA + ((g * 8 + kc) * 64 + lane) * 8);
                acc[g][0] = __builtin_amdgcn_mfma_f32_16x16x32_bf16(a, b0, acc[g][0], 0, 0, 0);
                acc[g][1] = __builtin_amdgcn_mfma_f32_16x16x32_bf16(a, b1, acc[g][1], 0, 0, 0);
            }
        }
#pragma unroll
        for (int g = 0; g < 4; ++g) {
#pragma unroll
            for (int t = 0; t < 2; ++t) {
                int n = w * 32 + t * 16 + col;
                float bb = fb[256 + n];
                int base = ((g * 4 + w) * 64 + (t * 2 + (col >> 3)) * 16) * 8 + (col & 7);
#pragma unroll
                for (int r = 0; r < 4; ++r) {
                    int mrow = quad * 4 + r;
                    sM[base + mrow * 8] = f2bf(silu(acc[g][t][r] + bb));
                }
            }
        }
        __syncthreads();

        f32x4 acc2[4][2] = {};
#pragma unroll
        for (int kc = 0; kc < 4; ++kc) {
            bf16x8 b0 = *(const bf16x8*)(Wn2s + ((kc * 8 + nt0)     * 64 + lane) * 8);
            bf16x8 b1 = *(const bf16x8*)(Wn2s + ((kc * 8 + nt0 + 1) * 64 + lane) * 8);
#pragma unroll
            for (int g = 0; g < 4; ++g) {
                bf16x8 a = *(const bf16x8*)(sM + ((g * 4 + kc) * 64 + lane) * 8);
                acc2[g][0] = __builtin_amdgcn_mfma_f32_16x16x32_bf16(a, b0, acc2[g][0], 0, 0, 0);
                acc2[g][1] = __builtin_amdgcn_mfma_f32_16x16x32_bf16(a, b1, acc2[g][1], 0, 0, 0);
            }
        }
#pragma unroll
        for (int g = 0; g < 4; ++g) {
#pragma unroll
            for (int t = 0; t < 2; ++t) {
                int n = w * 32 + t * 16 + col;
                float bb = fb[384 + n];
#pragma unroll
                for (int r = 0; r < 4; ++r) {
                    int ml2 = g * 16 + quad * 4 + r;
                    int node = n0 + ml2;
                    if (node < NN) {
                        size_t oi = (size_t)node * 128 + n;
                        float x = acc2[g][t][r] + bb + hf[oi];
                        if (isf) outf[oi] = x; else outu[oi] = f2bf(x);
                    }
                }
            }
        }
    }
}

extern "C" void kernel_launch(void* const* d_in, const int* in_sizes, int n_in,
                              void* d_out, int out_size, void* d_ws, size_t ws_size,
                              hipStream_t stream) {
    const void* xz  = d_in[0];
    const void* h   = d_in[1];
    const void* We1 = d_in[2];
    const void* be1 = d_in[3];
    const void* We2 = d_in[4];
    const void* be2 = d_in[5];
    const void* Wn1 = d_in[6];
    const void* bn1 = d_in[7];
    const void* Wn2 = d_in[8];
    const void* bn2 = d_in[9];
    const int*  ei  = (const int*)d_in[10];
    const int* erow = ei;
    const int* ecol = ei + EE;

    // workspace layout (256B-aligned chunks)
    char* base = (char*)d_ws;
    size_t cur = 0;
    auto alloc = [&](size_t bytes) { size_t o = cur; cur = (cur + bytes + 255) & ~(size_t)255; return o; };
    int*    flag = (int*)   (base + alloc(16));
    float*  agg  = (float*) (base + alloc((size_t)NN * 128 * 4));
    float*  cnt  = (float*) (base + alloc((size_t)NN * 4));
    float*  hf   = (float*) (base + alloc((size_t)NN * 128 * 4));
    ushort* hb   = (ushort*)(base + alloc((size_t)NN * 128 * 2));
    float*  xzf  = (float*) (base + alloc((size_t)NN * 3 * 4));
    ushort* We1s = (ushort*)(base + alloc(32768 * 2));
    ushort* We2s = (ushort*)(base + alloc(16384 * 2));
    ushort* Wn1s = (ushort*)(base + alloc(32768 * 2));
    ushort* Wn2s = (ushort*)(base + alloc(16384 * 2));
    float*  fb   = (float*) (base + alloc(640 * 4));

    (void)hipMemsetAsync(agg, 0, (size_t)NN * 128 * sizeof(float), stream);
    (void)hipMemsetAsync(cnt, 0, (size_t)NN * sizeof(float), stream);

    detect_kernel<<<1, 256, 0, stream>>>((const ushort*)xz, flag);
    ingest_h<<<(NN * 128 + 255) / 256, 256, 0, stream>>>(h, flag, hb, hf);
    ingest_xz<<<(NN * 3 + 255) / 256, 256, 0, stream>>>(xz, flag, xzf);
    ingest_misc<<<1, 256, 0, stream>>>(be1, be2, bn1, bn2, We1, flag, fb);
    swizzle_kernel<<<48, 256, 0, stream>>>(We1, We2, Wn1, Wn2, flag, We1s, We2s, Wn1s, Wn2s);
    count_kernel<<<EE / 256, 256, 0, stream>>>(erow, cnt);
    edge_kernel<<<768, 256, 0, stream>>>(hb, xzf, erow, ecol, We1s, We2s, fb, agg);
    node_kernel<<<782, 256, 0, stream>>>(hb, hf, agg, cnt, Wn1s, Wn2s, fb, flag, d_out);
}